// Round 10
// baseline (62.304 us; speedup 1.0000x reference)
//
#include <hip/hip_runtime.h>

#define B 64
#define T 4096
#define AD 1024   // ATTN_RNN_DIM
#define HD 256    // HYPERNET_DIM
#define CH 32
#define KS 31
#define OD 128
#define PADW 15
#define CWN (CH*KS)   // 992
#define TILE_T 128
#define NTILE (T / TILE_T)   // 32

// ---------------- Kernel A: h[b,j] = tanh(dot(query[b,:], W1[j,:]) + b1[j])
__global__ __launch_bounds__(256) void k_hyper1(const float* __restrict__ q,
        const float* __restrict__ W1, const float* __restrict__ b1,
        float* __restrict__ h) {
    int wid  = blockIdx.x * 4 + (threadIdx.x >> 6);
    int lane = threadIdx.x & 63;
    int b = wid >> 8;
    int j = wid & 255;
    const float4* qr = (const float4*)(q  + (size_t)b * AD);
    const float4* wr = (const float4*)(W1 + (size_t)j * AD);
    float s = 0.f;
    #pragma unroll
    for (int m = 0; m < 4; ++m) {
        float4 a = qr[m * 64 + lane];
        float4 w = wr[m * 64 + lane];
        s += a.x * w.x + a.y * w.y + a.z * w.z + a.w * w.w;
    }
    #pragma unroll
    for (int off = 32; off > 0; off >>= 1)
        s += __shfl_down(s, off, 64);
    if (lane == 0) h[b * HD + j] = tanhf(s + b1[j]);
}

// ---------------- Kernel B (fused cw+G): block (b,oct) owns k in [4*oct, min(4*oct+4,31))
// wave-cooperative cw rows: lane-split f4 dot + shfl_xor reduce (coalesced W2)
__global__ __launch_bounds__(256) void k_cwG(const float* __restrict__ h,
        const float* __restrict__ W2, const float* __restrict__ b2,
        const float* __restrict__ Wfc, float* __restrict__ Gt) {
    int bid = blockIdx.x;                 // 512 blocks: xcd-aligned with k_conv
    int xcd = bid & 7, idx = bid >> 3;    // idx 0..63
    int b   = xcd * 8 + (idx >> 3);
    int oct = idx & 7;
    int tid = threadIdx.x;
    int lane = tid & 63, w = tid >> 6;
    __shared__ float hs[HD];              // 1 KB
    __shared__ float cwl[CH * 4];         // [c][kl], 512 B
    __shared__ float wfs_t[CH * OD];      // [c][o], 16 KB

    hs[tid] = h[(size_t)b * HD + tid];
    #pragma unroll
    for (int p = 0; p < 16; ++p) {
        int i2 = p * 256 + tid;
        int o = i2 >> 5, c = i2 & 31;
        wfs_t[c * OD + o] = Wfc[i2];
    }
    __syncthreads();

    // 128 rows (c,kl): n = w*32 + i; coalesced: lane l reads W2[r][4l..4l+4)
    const float4* hs4 = (const float4*)hs;
    float4 hv = hs4[lane];
    #pragma unroll
    for (int i = 0; i < 32; ++i) {
        int n = w * 32 + i;
        int c = n >> 2, kl = n & 3;
        int kg = oct * 4 + kl;
        if (kg < KS) {
            int r = c * KS + kg;
            float4 wv = ((const float4*)(W2 + (size_t)r * HD))[lane];
            float s = wv.x * hv.x + wv.y * hv.y + wv.z * hv.z + wv.w * hv.w;
            #pragma unroll
            for (int m = 32; m > 0; m >>= 1)
                s += __shfl_xor(s, m, 64);
            if (lane == 0) cwl[c * 4 + kl] = s + b2[r];
        }
    }
    __syncthreads();

    // G: 512 outputs (kl,o); broadcast cwl + stride-1 wfs_t
    #pragma unroll
    for (int p = 0; p < 2; ++p) {
        int i2 = p * 256 + tid;
        int kl = i2 >> 7, o = i2 & 127;
        int kg = oct * 4 + kl;
        if (kg < KS) {
            float s = 0.f;
            #pragma unroll
            for (int c = 0; c < CH; ++c)
                s += wfs_t[c * OD + o] * cwl[c * 4 + kl];
            Gt[(size_t)b * (KS * OD) + kg * OD + o] = s;
        }
    }
}

// ---------------- Kernel C: out[b,t,o] = sum_k Gt[b,k,o]*pa[b,t+k-15] + bfc[o]
// anti-convoy: lane owns o2=lane*2, one full 512B-row f2 store per ~250 cyc,
// g2[31] in VGPRs, no barriers after prologue -> waves drift, stores stream
__global__ __launch_bounds__(256, 3) void k_conv(const float* __restrict__ pa_g,
        const float* __restrict__ Gt, const float* __restrict__ bfc,
        float* __restrict__ out) {
    // XCD swizzle: grid 2048 = 8 XCDs x 256; XCD x gets b in [8x, 8x+8)
    int bid  = blockIdx.x;
    int sid  = (bid & 7) * 256 + (bid >> 3);
    int b    = sid >> 5;
    int tile = sid & 31;
    int t0   = tile * TILE_T;
    int tid  = threadIdx.x;
    int lane = tid & 63, w = tid >> 6;
    __shared__ float pa[160];

    if (tid < TILE_T + 30) {
        int gg = t0 + tid - PADW;
        pa[tid] = (gg >= 0 && gg < T) ? pa_g[(size_t)b * T + gg] : 0.f;
    }
    int o2 = lane * 2;
    float2 g2[KS];
    const float* gp = Gt + (size_t)b * (KS * OD) + o2;
    #pragma unroll
    for (int k = 0; k < KS; ++k)
        g2[k] = *(const float2*)(gp + k * OD);        // 512B/wave, L2-hot
    float2 bias = *(const float2*)(bfc + o2);
    __syncthreads();

    float* outb = out + ((size_t)b * T + t0) * OD + o2;
    #pragma unroll
    for (int it = 0; it < 4; ++it) {
        int r0 = it * 32 + w * 8;                     // wave-private 8-row group
        float pw[40];
        const float4* pv = (const float4*)(pa + r0);  // r0 % 8 == 0 -> aligned
        #pragma unroll
        for (int q4 = 0; q4 < 10; ++q4) {             // broadcast reads: free
            float4 v = pv[q4];
            pw[q4*4+0] = v.x; pw[q4*4+1] = v.y; pw[q4*4+2] = v.z; pw[q4*4+3] = v.w;
        }
        #pragma unroll
        for (int r = 0; r < 8; ++r) {
            float2 a = bias;
            #pragma unroll
            for (int k = 0; k < KS; ++k) {
                float p = pw[r + k];
                a.x += g2[k].x * p;
                a.y += g2[k].y * p;
            }
            // 64 lanes x 8B = one full 512B row, spread through compute
            *(float2*)(outb + (size_t)(r0 + r) * OD) = a;
        }
    }
}

extern "C" void kernel_launch(void* const* d_in, const int* in_sizes, int n_in,
                              void* d_out, int out_size, void* d_ws, size_t ws_size,
                              hipStream_t stream) {
    const float* query = (const float*)d_in[0];
    const float* prev  = (const float*)d_in[1];
    const float* W1    = (const float*)d_in[2];
    const float* b1    = (const float*)d_in[3];
    const float* W2    = (const float*)d_in[4];
    const float* b2    = (const float*)d_in[5];
    const float* Wfc   = (const float*)d_in[6];
    const float* bfc   = (const float*)d_in[7];
    float* out = (float*)d_out;

    float* h  = (float*)d_ws;          // 16384 floats
    float* Gt = h + B * HD;            // 253952 floats

    k_hyper1<<<dim3(4096), dim3(256), 0, stream>>>(query, W1, b1, h);
    k_cwG   <<<dim3(B * 8), dim3(256), 0, stream>>>(h, W2, b2, Wfc, Gt);
    k_conv  <<<dim3(B * NTILE), dim3(256), 0, stream>>>(prev, Gt, bfc, out);
}

// Round 11
// 52.716 us; speedup vs baseline: 1.1819x; 1.1819x over previous
//
#include <hip/hip_runtime.h>

#define B 64
#define T 4096
#define AD 1024   // ATTN_RNN_DIM
#define HD 256    // HYPERNET_DIM
#define CH 32
#define KS 31
#define OD 128
#define PADW 15
#define CWN (CH*KS)   // 992
#define TILE_T 128
#define NTILE (T / TILE_T)   // 32

// LDS-only barrier: orders ds_write->ds_read across waves WITHOUT draining
// global stores (vanilla __syncthreads emits s_waitcnt vmcnt(0) first, which
// serializes compute against the HBM write queue every chunk).
#define LDS_BARRIER() asm volatile("s_waitcnt lgkmcnt(0)\n\ts_barrier" ::: "memory")

// ---------------- Kernel A: h[b,j] = tanh(dot(query[b,:], W1[j,:]) + b1[j])
__global__ __launch_bounds__(256) void k_hyper1(const float* __restrict__ q,
        const float* __restrict__ W1, const float* __restrict__ b1,
        float* __restrict__ h) {
    int wid  = blockIdx.x * 4 + (threadIdx.x >> 6);
    int lane = threadIdx.x & 63;
    int b = wid >> 8;
    int j = wid & 255;
    const float4* qr = (const float4*)(q  + (size_t)b * AD);
    const float4* wr = (const float4*)(W1 + (size_t)j * AD);
    float s = 0.f;
    #pragma unroll
    for (int m = 0; m < 4; ++m) {
        float4 a = qr[m * 64 + lane];
        float4 w = wr[m * 64 + lane];
        s += a.x * w.x + a.y * w.y + a.z * w.z + a.w * w.w;
    }
    #pragma unroll
    for (int off = 32; off > 0; off >>= 1)
        s += __shfl_down(s, off, 64);
    if (lane == 0) h[b * HD + j] = tanhf(s + b1[j]);
}

// ---------------- Kernel B (fused cw+G): block (b,q) owns k in [8q, min(8q+8,31))
// computes its own cw slice {c*KS+k} into LDS, then G[k,o] for its k-range.
__global__ __launch_bounds__(256) void k_cwG(const float* __restrict__ h,
        const float* __restrict__ W2, const float* __restrict__ b2,
        const float* __restrict__ Wfc, float* __restrict__ Gt) {
    int b = blockIdx.x >> 2;
    int q = blockIdx.x & 3;
    int tid = threadIdx.x;
    __shared__ float hs[HD];           // 1 KB
    __shared__ float cwl[CH * 8];      // [c][kk], 1 KB
    __shared__ float wfs_t[CH * OD];   // [c][o], 16 KB
    hs[tid] = h[(size_t)b * HD + tid];
    #pragma unroll
    for (int p = 0; p < 16; ++p) {
        int idx = p * 256 + tid;
        int o = idx >> 5, c = idx & 31;
        wfs_t[c * OD + o] = Wfc[idx];
    }
    __syncthreads();
    {
        int c = tid >> 3, kk = tid & 7;
        int k = q * 8 + kk;
        if (k < KS) {
            int r = c * KS + k;
            const float4* wr  = (const float4*)(W2 + (size_t)r * HD);
            const float4* hs4 = (const float4*)hs;
            float s = 0.f;
            #pragma unroll
            for (int m = 0; m < HD / 4; ++m) {
                float4 w = wr[m], hv = hs4[m];
                s += w.x * hv.x + w.y * hv.y + w.z * hv.z + w.w * hv.w;
            }
            cwl[c * 8 + kk] = s + b2[r];
        }
    }
    __syncthreads();
    #pragma unroll
    for (int p = 0; p < 4; ++p) {
        int idx = p * 256 + tid;
        int kl = idx >> 7, o = idx & 127;
        int kg = q * 8 + kl;
        if (kg < KS) {
            float s = 0.f;
            #pragma unroll
            for (int c = 0; c < CH; ++c)
                s += wfs_t[c * OD + o] * cwl[c * 8 + kl];   // bcast + stride-1
            Gt[(size_t)b * (KS * OD) + kg * OD + o] = s;
        }
    }
}

// ---------------- Kernel C: out[b,t,o] = sum_k Gt[b,k,o]*pa[b,t+k-15] + bfc[o]
// R9 chunk structure, but per-chunk barrier is LDS-only: global stores stay
// in flight under the next chunk's compute (counted-vmcnt principle)
__device__ __forceinline__ void compute_chunk(const float* pa, int s0, float base,
                                              const float (&g)[KS], float (&acc)[8]) {
    float pw[40];
    const float4* lp = (const float4*)(pa + s0);   // s0 % 8 == 0 -> aligned
    #pragma unroll
    for (int q4 = 0; q4 < 10; ++q4) {
        float4 v = lp[q4];
        pw[q4*4+0] = v.x; pw[q4*4+1] = v.y; pw[q4*4+2] = v.z; pw[q4*4+3] = v.w;
    }
    #pragma unroll
    for (int tt = 0; tt < 8; ++tt) {
        float a = base;
        #pragma unroll
        for (int k = 0; k < KS; ++k)
            a += g[k] * pw[tt + k];
        acc[tt] = a;
    }
}

__global__ __launch_bounds__(256, 4) void k_conv(const float* __restrict__ pa_g,
        const float* __restrict__ Gt, const float* __restrict__ bfc,
        float* __restrict__ out) {
    // XCD swizzle: grid 2048 = 8 XCDs x 256; each XCD gets 8 whole batches
    int bid  = blockIdx.x;
    int sid  = (bid & 7) * 256 + (bid >> 3);
    int b    = sid >> 5;          // 32 tiles per b
    int tile = sid & 31;
    int t0   = tile * TILE_T;
    int tid  = threadIdx.x;
    __shared__ float tileo[64][128];      // 32 KB
    __shared__ float pa[TILE_T + 32];     // 158 used

    if (tid < TILE_T + 30) {
        int gg = t0 + tid - PADW;
        pa[tid] = (gg >= 0 && gg < T) ? pa_g[(size_t)b * T + gg] : 0.f;
    }
    int o = tid & 127, half = tid >> 7;
    float g[KS];
    #pragma unroll
    for (int k = 0; k < KS; ++k)
        g[k] = Gt[(size_t)b * (KS * OD) + k * OD + o];   // coalesced, L2-hot
    float base = bfc[o];
    __syncthreads();

    #pragma unroll
    for (int pass = 0; pass < 2; ++pass) {
        const float* pap = pa + pass * 64;               // keeps 16B alignment
        size_t obase = ((size_t)b * T + t0 + pass * 64) * OD;
        #pragma unroll
        for (int c = 0; c < 4; ++c) {
            int s0 = half * 32 + c * 8;
            float acc[8];
            compute_chunk(pap, s0, base, g, acc);
            #pragma unroll
            for (int tt = 0; tt < 8; ++tt)
                tileo[s0 + tt][o] = acc[tt];             // 2-way alias: free
            LDS_BARRIER();   // LDS-only: stores from prior chunks keep flying
            // store the 16 completed rows, 1KB contiguous per wave-instr
            #pragma unroll
            for (int j = 0; j < 2; ++j) {
                int f  = j * 256 + tid;
                int rl = f >> 5, c4 = f & 31;
                int row = (j == 0) ? (c * 8 + rl) : (32 + c * 8 + (rl - 8));
                float4 v = *(const float4*)&tileo[row][c4 * 4];
                *(float4*)(out + obase + (size_t)row * OD + c4 * 4) = v;
            }
            // no barrier after stores: next chunk writes disjoint LDS rows,
            // and pass-1 reuse is >=1 barrier behind the consuming ds_reads
        }
    }
}

extern "C" void kernel_launch(void* const* d_in, const int* in_sizes, int n_in,
                              void* d_out, int out_size, void* d_ws, size_t ws_size,
                              hipStream_t stream) {
    const float* query = (const float*)d_in[0];
    const float* prev  = (const float*)d_in[1];
    const float* W1    = (const float*)d_in[2];
    const float* b1    = (const float*)d_in[3];
    const float* W2    = (const float*)d_in[4];
    const float* b2    = (const float*)d_in[5];
    const float* Wfc   = (const float*)d_in[6];
    const float* bfc   = (const float*)d_in[7];
    float* out = (float*)d_out;

    float* h  = (float*)d_ws;          // 16384 floats
    float* Gt = h + B * HD;            // 253952 floats

    k_hyper1<<<dim3(4096), dim3(256), 0, stream>>>(query, W1, b1, h);
    k_cwG   <<<dim3(B * 4), dim3(256), 0, stream>>>(h, W2, b2, Wfc, Gt);
    k_conv  <<<dim3(B * NTILE), dim3(256), 0, stream>>>(prev, Gt, bfc, out);
}